// Round 7
// baseline (308.331 us; speedup 1.0000x reference)
//
#include <hip/hip_runtime.h>

using u16    = unsigned short;
using short8 = __attribute__((ext_vector_type(8))) short;
using f32x4  = __attribute__((ext_vector_type(4))) float;
using f32x16 = __attribute__((ext_vector_type(16))) float;

#define MFMA16(a, b, c) __builtin_amdgcn_mfma_f32_16x16x32_bf16(a, b, c, 0, 0, 0)
#define MFMA32(a, b, c) __builtin_amdgcn_mfma_f32_32x32x16_bf16(a, b, c, 0, 0, 0)

// 0.125 (= D^-0.5) * log2(e): folded into Q so softmax uses exp2 directly.
#define QSCALE 0.18033688011112042f

__device__ inline u16 f2bf(float f) {
  union { float f; unsigned u; } v; v.f = f;
  unsigned r = v.u + 0x7fffu + ((v.u >> 16) & 1u);  // RTN-even
  return (u16)(r >> 16);
}

// async global->LDS, 16B/lane; LDS dest = wave-uniform base + lane*16
__device__ __forceinline__ void load_lds16(const u16* g, u16* l) {
  __builtin_amdgcn_global_load_lds((const __attribute__((address_space(1))) void*)g,
                                   (__attribute__((address_space(3))) void*)l, 16, 0, 0);
}

// packed f32 pair -> bf16x2 word (lo in low 16, hi in high 16), RTNE
__device__ __forceinline__ unsigned cvt_pk_bf16(float lo, float hi) {
  unsigned r;
  asm("v_cvt_pk_bf16_f32 %0, %1, %2" : "=v"(r) : "v"(lo), "v"(hi));
  return r;
}

// swap a's high 32 lanes with b's low 32 lanes (v_permlane32_swap_b32)
__device__ __forceinline__ void plswap(unsigned& a, unsigned& b) {
  auto r = __builtin_amdgcn_permlane32_swap(a, b, false, false);
  a = r[0];
  b = r[1];
}

// ------------------------------------------------------------ f32 -> bf16
// Both x and y in one launch: blockIdx.y selects the tensor.
__global__ __launch_bounds__(256) void cvt2_k(const float* __restrict__ s0,
                                              const float* __restrict__ s1,
                                              u16* __restrict__ d0,
                                              u16* __restrict__ d1) {
  const float* src = blockIdx.y ? s1 : s0;
  u16* dst = blockIdx.y ? d1 : d0;
  const int i = (blockIdx.x * 256 + threadIdx.x) * 8;
  const float4 a = *(const float4*)&src[i];
  const float4 b = *(const float4*)&src[i + 4];
  short8 o;
  o[0] = (short)f2bf(a.x); o[1] = (short)f2bf(a.y);
  o[2] = (short)f2bf(a.z); o[3] = (short)f2bf(a.w);
  o[4] = (short)f2bf(b.x); o[5] = (short)f2bf(b.y);
  o[6] = (short)f2bf(b.z); o[7] = (short)f2bf(b.w);
  *(short8*)&dst[i] = o;
}

// ------------------------------------------- f32 [R][C] -> bf16 [C][R]
__global__ __launch_bounds__(256) void cvtT_k(const float* __restrict__ src,
                                              u16* __restrict__ dst, int R, int C) {
  __shared__ float t[64][65];
  const int c0 = blockIdx.x * 64, r0 = blockIdx.y * 64;
  const int lc = threadIdx.x & 63, g = threadIdx.x >> 6;
#pragma unroll
  for (int i = 0; i < 16; ++i) {
    const int r = g + i * 4;
    t[r][lc] = src[(size_t)(r0 + r) * C + c0 + lc];
  }
  __syncthreads();
#pragma unroll
  for (int i = 0; i < 16; ++i) {
    const int c = g + i * 4;
    dst[(size_t)(c0 + c) * R + r0 + lc] = f2bf(t[lc][c]);
  }
}

// ---------------------------------------------------------------- GEMM 128²
// C[m][n] = sum_k A[m][k] * Bt[n][k].  K = 1024 bf16, strides 1024.
// Block tile 128x128, BK=64; 4 waves (2x2), wave 64x64 via 4x4 MFMA 16x16x32.
// Single-buffer staging (m97 structure; R5: 256² 8-phase regressed here).
// T1 XCD-chunked 1-D grid (R6: ~neutral, kept -- free and mechanism-sound).
template <int MODE>
__global__ __launch_bounds__(256, 2) void gemm_k(
    const u16* __restrict__ A0, const u16* __restrict__ A1,
    const u16* __restrict__ Bt,
    u16* __restrict__ q_out, u16* __restrict__ k_out, u16* __restrict__ v_out,
    float* __restrict__ c0, float* __restrict__ c1,
    const float* __restrict__ bias,
    const float* __restrict__ res0, const float* __restrict__ res1) {
  __shared__ alignas(16) u16 lA[128 * 64];
  __shared__ alignas(16) u16 lB[128 * 64];

  const int nx = (MODE == 0) ? 24 : 8;        // N/128
  const int nb = nx * 32 * 2;                  // total tiles (y=32, z=2)
  const int bi = blockIdx.x;
  const int L  = (bi & 7) * (nb >> 3) + (bi >> 3);
  const int xt = L % nx;
  const int yt = (L / nx) & 31;
  const int z  = L / (nx * 32);

  const u16* A = z ? A1 : A0;
  float* c_out = z ? c1 : c0;
  const float* res = z ? res1 : res0;
  const int head_base = z * 32;

  const int tid = threadIdx.x;
  const int lane = tid & 63, wave = tid >> 6;
  const int quad = lane >> 4, l16 = lane & 15;
  const int lsw = (l16 & 7) * 8;
  const int wm = (wave >> 1) * 64, wn = (wave & 1) * 64;
  const int bn0 = xt * 128, bm0 = yt * 128;
  const int srow = lane >> 3;
  const int sg = (lane & 7) ^ srow;

  f32x4 acc[4][4] = {};

  for (int k0 = 0; k0 < 1024; k0 += 64) {
    __syncthreads();
#pragma unroll
    for (int it = 0; it < 4; ++it) {
      const int rb = wave * 32 + it * 8;
      const int r = rb + srow;
      load_lds16(&A[(size_t)(bm0 + r) * 1024 + k0 + sg * 8], &lA[rb * 64]);
      load_lds16(&Bt[(size_t)(bn0 + r) * 1024 + k0 + sg * 8], &lB[rb * 64]);
    }
    asm volatile("s_waitcnt vmcnt(0)" ::: "memory");
    __syncthreads();
#pragma unroll
    for (int kt = 0; kt < 2; ++kt) {
      short8 af[4], bfr[4];
#pragma unroll
      for (int i = 0; i < 4; ++i) {
        const int go = ((kt * 4 + quad) * 8) ^ lsw;
        af[i]  = *(const short8*)&lA[(wm + i * 16 + l16) * 64 + go];
        bfr[i] = *(const short8*)&lB[(wn + i * 16 + l16) * 64 + go];
      }
#pragma unroll
      for (int i = 0; i < 4; ++i)
#pragma unroll
        for (int j = 0; j < 4; ++j)
          acc[i][j] = MFMA16(af[i], bfr[j], acc[i][j]);
    }
  }

#pragma unroll
  for (int i = 0; i < 4; ++i) {
    const int row = bm0 + wm + i * 16 + quad * 4;
#pragma unroll
    for (int j = 0; j < 4; ++j) {
      const int col = bn0 + wn + j * 16 + l16;
#pragma unroll
      for (int r = 0; r < 4; ++r) {
        const float v = acc[i][j][r];
        const int m = row + r;
        if (MODE == 0) {
          const int which = col >> 10;
          const int h = (col >> 6) & 15, d = col & 63;
          const int b = m >> 11, n = m & 2047;
          const size_t hh = (size_t)(head_base + b * 16 + h);
          if (which == 0)      q_out[(hh * 2048 + n) * 64 + d] = f2bf(v * QSCALE);
          else if (which == 1) k_out[(hh * 2048 + n) * 64 + d] = f2bf(v);
          else                 v_out[(hh * 64 + d) * 2048 + n] = f2bf(v);  // V^T
        } else {
          const size_t idx = (size_t)m * 1024 + col;
          c_out[idx] = v + bias[col] + res[idx];
        }
      }
    }
  }
}

// ---------------------------------------------------------------- attention
// (R4 structure: XCD-chunked grid, dbuf K/V prefetch, T12 in-register P
// exchange, conflict-free LDS swizzle, native exp2.)
//
// R7: softmax denominator moved onto the MFMA pipe.  l[q] = sum_key P[q][key]
// is computed as MFMA32(pa[st], ones_B, lacc) -- with B[k][n]=1 every output
// column holds the row sum, and lacc's reg->row mapping equals oacc's, so the
// epilogue divides by lacc[r] directly.  Replaces 32 v_add_f32 + 1 shfl_xor
// per tile + 16 epilogue shuffles (on the 52%-busy VALU issue stream) with
// 4 MFMA32/tile (on the 35%-busy MFMA pipe), and deletes the serial rs chain
// between exp2 and PV.  l is now summed over the same bf16-rounded P that PV
// consumes (self-consistent numerics).
__global__ __launch_bounds__(256, 4) void attn_k(const u16* __restrict__ Q,
                                                 const u16* __restrict__ K,
                                                 const u16* __restrict__ V,
                                                 u16* __restrict__ O) {
  __shared__ alignas(16) u16 kT[2][64 * 64];   // [key][d], granule-swizzled
  __shared__ alignas(16) u16 vT[2][64 * 64];   // [d][key], granule-swizzled

  const int tid = threadIdx.x;
  const int lane = tid & 63, wave = tid >> 6;
  const int qn = lane & 31, h = lane >> 5;

  // XCD-chunked swizzle (bijective: 1024 = 8 XCDs x 128): XCD c owns
  // logical tiles [128c,128c+128) = 16 q-tiles x 8 consecutive heads.
  const int d0 = blockIdx.x;
  const int swz = ((d0 & 7) << 7) | (d0 >> 3);
  const int qx = swz & 15;          // q-tile
  const int hh = (swz >> 4) & 15;   // head-in-group
  const int z  = swz >> 8;          // (s,b)
  const int s = z >> 1, b = z & 1;

  const int head_qk = z * 16 + hh;
  const int head_v  = (z ^ 2) * 16 + hh;            // cross-swapped values
  const u16* Qh = Q + (size_t)head_qk * 2048 * 64;
  const u16* Kh = K + (size_t)head_qk * 2048 * 64;
  const u16* Vh = V + (size_t)head_v * 64 * 2048;   // [d][n]
  const int qr0 = qx * 128 + wave * 32;

  // Q as persistent B-frags: B[k=d=f*16+h*8+j][n=q=qn]
  short8 qf[4];
#pragma unroll
  for (int f = 0; f < 4; ++f)
    qf[f] = *(const short8*)&Qh[(size_t)(qr0 + qn) * 64 + f * 16 + h * 8];

  // all-ones bf16 B-fragment for the denominator MFMA
  short8 ones;
#pragma unroll
  for (int j = 0; j < 8; ++j) ones[j] = (short)0x3F80;

  f32x16 oacc[2] = {};
  f32x16 lacc = {};

  const int srow = lane >> 3;

  union PU { unsigned u[4]; short8 s; };

  auto stage = [&](int buf, int j0) {
#pragma unroll
    for (int it = 0; it < 2; ++it) {
      const int rb = wave * 16 + it * 8;
      const int r = rb + srow;
      const int sgx = (lane & 7) ^ srow ^ (rb >> 3);  // inverse of read key
      load_lds16(&Kh[(size_t)(j0 + r) * 64 + sgx * 8], &kT[buf][rb * 64]);
      load_lds16(&Vh[(size_t)r * 2048 + j0 + sgx * 8], &vT[buf][rb * 64]);
    }
  };

  stage(0, 0);
  asm volatile("s_waitcnt vmcnt(0)" ::: "memory");
  __syncthreads();

  int cur = 0;
  for (int j0 = 0; j0 < 2048; j0 += 64) {
    if (j0 + 64 < 2048) stage(cur ^ 1, j0 + 64);  // prefetch under compute
    const u16* kb = kT[cur];
    const u16* vb = vT[cur];

    // S^T = K * Q^T: A = K rows (keys), B = Q.  2 key-tiles x 4 k-steps.
    f32x16 sacc[2] = {};
#pragma unroll
    for (int t = 0; t < 2; ++t) {
      const int row = t * 32 + qn;
      const int key = (row & 7) ^ (row >> 3);  // conflict-free swizzle key
#pragma unroll
      for (int kd = 0; kd < 4; ++kd) {
        const int go = ((kd * 2 + h) ^ key) * 8;
        const short8 kf = *(const short8*)&kb[row * 64 + go];
        sacc[t] = MFMA32(kf, qf[kd], sacc[t]);
      }
    }

    // p = exp2(s) via native v_exp_f32; pack to bf16 pairs in-register
    unsigned pw[2][8];
#pragma unroll
    for (int t = 0; t < 2; ++t)
#pragma unroll
      for (int j = 0; j < 8; ++j) {
        const float pa0 = __builtin_amdgcn_exp2f(sacc[t][2 * j]);
        const float pa1 = __builtin_amdgcn_exp2f(sacc[t][2 * j + 1]);
        pw[t][j] = cvt_pk_bf16(pa0, pa1);
      }

    // h-half exchange (T12): lane(h=0) holds keys ≡0..3 (mod 8), lane^32
    // holds ≡4..7.  swap(w[4e],w[4e+2]) / swap(w[4e+1],w[4e+3]) yields the
    // PV A-fragment pa[st][j] = P[q=qn][key=st*16+h*8+j] for st=2t+e.
    PU pa[4];
#pragma unroll
    for (int t = 0; t < 2; ++t)
#pragma unroll
      for (int e = 0; e < 2; ++e) {
        unsigned a0 = pw[t][4 * e + 0], a2 = pw[t][4 * e + 2];
        unsigned a1 = pw[t][4 * e + 1], a3 = pw[t][4 * e + 3];
        plswap(a0, a2);
        plswap(a1, a3);
        pa[2 * t + e].u[0] = a0; pa[2 * t + e].u[1] = a1;
        pa[2 * t + e].u[2] = a2; pa[2 * t + e].u[3] = a3;
      }

    // denominator on the MFMA pipe: lacc[q] += sum_key P[q][key]
#pragma unroll
    for (int st = 0; st < 4; ++st)
      lacc = MFMA32(pa[st].s, ones, lacc);

    // O += P * V: A = P[q][key], B = V[key][d] (from vT[d][key])
#pragma unroll
    for (int dt = 0; dt < 2; ++dt) {
      const int row = dt * 32 + qn;
      const int key = (row & 7) ^ (row >> 3);
#pragma unroll
      for (int st = 0; st < 4; ++st) {
        const int go = ((st * 2 + h) ^ key) * 8;
        const short8 vf = *(const short8*)&vb[row * 64 + go];
        oacc[dt] = MFMA32(pa[st].s, vf, oacc[dt]);
      }
    }

    asm volatile("s_waitcnt vmcnt(0)" ::: "memory");  // prefetch landed
    __syncthreads();  // all waves done reading cur; next buf visible
    cur ^= 1;
  }

  // epilogue: O[q][d]: row q=(reg&3)+8*(reg>>2)+4h, col d=dt*32+qn.
  // lacc[r] has the same reg->row mapping -> direct divide, no shuffles.
  u16* Ob = O + (size_t)s * 4096 * 1024;
#pragma unroll
  for (int r = 0; r < 16; ++r) {
    const int qrow = (r & 3) + 8 * (r >> 2) + 4 * h;
    const float inv = 1.f / lacc[r];
    const size_t base = (size_t)(b * 2048 + qr0 + qrow) * 1024 + hh * 64;
#pragma unroll
    for (int dt = 0; dt < 2; ++dt)
      Ob[base + dt * 32 + qn] = f2bf(oacc[dt][r] * inv);
  }
}

// ---------------------------------------------------------------- launch
extern "C" void kernel_launch(void* const* d_in, const int* in_sizes, int n_in,
                              void* d_out, int out_size, void* d_ws, size_t ws_size,
                              hipStream_t stream) {
  const float* x      = (const float*)d_in[0];   // [2,2048,1024] f32
  const float* y      = (const float*)d_in[1];
  const float* w_qkv  = (const float*)d_in[2];   // [1024,3072] f32
  const float* w_proj = (const float*)d_in[3];   // [1024,1024] f32
  const float* b_proj = (const float*)d_in[4];   // [1024] f32
  float* out = (float*)d_out;                    // 2 x [2,2048,1024] f32

  u16* xb     = (u16*)d_ws;
  u16* yb     = xb + 4194304;
  u16* Ob     = xb;                 // reuse: xb/yb dead after QKV GEMMs
  u16* wqkvT  = yb + 4194304;       // [3072][1024]
  u16* wprojT = wqkvT + 3145728;    // [1024][1024]
  u16* Qs     = wprojT + 1048576;   // [64][2048][64]
  u16* Ks     = Qs + 8388608;       // [64][2048][64]
  u16* Vs     = Ks + 8388608;       // [64][64][2048]  (transposed)

  cvt2_k<<<dim3(2048, 2), 256, 0, stream>>>(x, y, xb, yb);
  cvtT_k<<<dim3(48, 16), 256, 0, stream>>>(w_qkv, wqkvT, 1024, 3072);
  cvtT_k<<<dim3(16, 16), 256, 0, stream>>>(w_proj, wprojT, 1024, 1024);

  gemm_k<0><<<1536, 256, 0, stream>>>(xb, yb, wqkvT, Qs, Ks, Vs,
                                      nullptr, nullptr, nullptr,
                                      nullptr, nullptr);

  attn_k<<<1024, 256, 0, stream>>>(Qs, Ks, Vs, Ob);

  gemm_k<1><<<512, 256, 0, stream>>>(Ob, Ob + 4194304, wprojT,
                                     nullptr, nullptr, nullptr,
                                     out, out + 4194304, b_proj, x, y);
}

// Round 8
// 294.578 us; speedup vs baseline: 1.0467x; 1.0467x over previous
//
#include <hip/hip_runtime.h>

using u16    = unsigned short;
using short8 = __attribute__((ext_vector_type(8))) short;
using f32x4  = __attribute__((ext_vector_type(4))) float;
using f32x16 = __attribute__((ext_vector_type(16))) float;

#define MFMA16(a, b, c) __builtin_amdgcn_mfma_f32_16x16x32_bf16(a, b, c, 0, 0, 0)
#define MFMA32(a, b, c) __builtin_amdgcn_mfma_f32_32x32x16_bf16(a, b, c, 0, 0, 0)

// 0.125 (= D^-0.5) * log2(e): folded into Q so softmax uses exp2 directly.
#define QSCALE 0.18033688011112042f

__device__ inline u16 f2bf(float f) {
  union { float f; unsigned u; } v; v.f = f;
  unsigned r = v.u + 0x7fffu + ((v.u >> 16) & 1u);  // RTN-even
  return (u16)(r >> 16);
}

// async global->LDS, 16B/lane; LDS dest = wave-uniform base + lane*16
__device__ __forceinline__ void load_lds16(const u16* g, u16* l) {
  __builtin_amdgcn_global_load_lds((const __attribute__((address_space(1))) void*)g,
                                   (__attribute__((address_space(3))) void*)l, 16, 0, 0);
}

// packed f32 pair -> bf16x2 word (lo in low 16, hi in high 16), RTNE
__device__ __forceinline__ unsigned cvt_pk_bf16(float lo, float hi) {
  unsigned r;
  asm("v_cvt_pk_bf16_f32 %0, %1, %2" : "=v"(r) : "v"(lo), "v"(hi));
  return r;
}

// swap a's high 32 lanes with b's low 32 lanes (v_permlane32_swap_b32)
__device__ __forceinline__ void plswap(unsigned& a, unsigned& b) {
  auto r = __builtin_amdgcn_permlane32_swap(a, b, false, false);
  a = r[0];
  b = r[1];
}

// ------------------------------------------------------------ f32 -> bf16
// Both x and y in one launch: blockIdx.y selects the tensor.
__global__ __launch_bounds__(256) void cvt2_k(const float* __restrict__ s0,
                                              const float* __restrict__ s1,
                                              u16* __restrict__ d0,
                                              u16* __restrict__ d1) {
  const float* src = blockIdx.y ? s1 : s0;
  u16* dst = blockIdx.y ? d1 : d0;
  const int i = (blockIdx.x * 256 + threadIdx.x) * 8;
  const float4 a = *(const float4*)&src[i];
  const float4 b = *(const float4*)&src[i + 4];
  short8 o;
  o[0] = (short)f2bf(a.x); o[1] = (short)f2bf(a.y);
  o[2] = (short)f2bf(a.z); o[3] = (short)f2bf(a.w);
  o[4] = (short)f2bf(b.x); o[5] = (short)f2bf(b.y);
  o[6] = (short)f2bf(b.z); o[7] = (short)f2bf(b.w);
  *(short8*)&dst[i] = o;
}

// ------------------------------------------- f32 [R][C] -> bf16 [C][R]
__global__ __launch_bounds__(256) void cvtT_k(const float* __restrict__ src,
                                              u16* __restrict__ dst, int R, int C) {
  __shared__ float t[64][65];
  const int c0 = blockIdx.x * 64, r0 = blockIdx.y * 64;
  const int lc = threadIdx.x & 63, g = threadIdx.x >> 6;
#pragma unroll
  for (int i = 0; i < 16; ++i) {
    const int r = g + i * 4;
    t[r][lc] = src[(size_t)(r0 + r) * C + c0 + lc];
  }
  __syncthreads();
#pragma unroll
  for (int i = 0; i < 16; ++i) {
    const int c = g + i * 4;
    dst[(size_t)(c0 + c) * R + r0 + lc] = f2bf(t[lc][c]);
  }
}

// ---------------------------------------------------------------- GEMM 128²
// C[m][n] = sum_k A[m][k] * Bt[n][k].  K = 1024 bf16, strides 1024.
// Block tile 128x128, BK=64; 4 waves (2x2), wave 64x64 via 4x4 MFMA 16x16x32.
// Single-buffer staging (m97 structure; R5: 256² 8-phase regressed here).
// T1 XCD-chunked 1-D grid (R6: ~neutral, kept -- free and mechanism-sound).
template <int MODE>
__global__ __launch_bounds__(256, 2) void gemm_k(
    const u16* __restrict__ A0, const u16* __restrict__ A1,
    const u16* __restrict__ Bt,
    u16* __restrict__ q_out, u16* __restrict__ k_out, u16* __restrict__ v_out,
    float* __restrict__ c0, float* __restrict__ c1,
    const float* __restrict__ bias,
    const float* __restrict__ res0, const float* __restrict__ res1) {
  __shared__ alignas(16) u16 lA[128 * 64];
  __shared__ alignas(16) u16 lB[128 * 64];

  const int nx = (MODE == 0) ? 24 : 8;        // N/128
  const int nb = nx * 32 * 2;                  // total tiles (y=32, z=2)
  const int bi = blockIdx.x;
  const int L  = (bi & 7) * (nb >> 3) + (bi >> 3);
  const int xt = L % nx;
  const int yt = (L / nx) & 31;
  const int z  = L / (nx * 32);

  const u16* A = z ? A1 : A0;
  float* c_out = z ? c1 : c0;
  const float* res = z ? res1 : res0;
  const int head_base = z * 32;

  const int tid = threadIdx.x;
  const int lane = tid & 63, wave = tid >> 6;
  const int quad = lane >> 4, l16 = lane & 15;
  const int lsw = (l16 & 7) * 8;
  const int wm = (wave >> 1) * 64, wn = (wave & 1) * 64;
  const int bn0 = xt * 128, bm0 = yt * 128;
  const int srow = lane >> 3;
  const int sg = (lane & 7) ^ srow;

  f32x4 acc[4][4] = {};

  for (int k0 = 0; k0 < 1024; k0 += 64) {
    __syncthreads();
#pragma unroll
    for (int it = 0; it < 4; ++it) {
      const int rb = wave * 32 + it * 8;
      const int r = rb + srow;
      load_lds16(&A[(size_t)(bm0 + r) * 1024 + k0 + sg * 8], &lA[rb * 64]);
      load_lds16(&Bt[(size_t)(bn0 + r) * 1024 + k0 + sg * 8], &lB[rb * 64]);
    }
    asm volatile("s_waitcnt vmcnt(0)" ::: "memory");
    __syncthreads();
#pragma unroll
    for (int kt = 0; kt < 2; ++kt) {
      short8 af[4], bfr[4];
#pragma unroll
      for (int i = 0; i < 4; ++i) {
        const int go = ((kt * 4 + quad) * 8) ^ lsw;
        af[i]  = *(const short8*)&lA[(wm + i * 16 + l16) * 64 + go];
        bfr[i] = *(const short8*)&lB[(wn + i * 16 + l16) * 64 + go];
      }
#pragma unroll
      for (int i = 0; i < 4; ++i)
#pragma unroll
        for (int j = 0; j < 4; ++j)
          acc[i][j] = MFMA16(af[i], bfr[j], acc[i][j]);
    }
  }

#pragma unroll
  for (int i = 0; i < 4; ++i) {
    const int row = bm0 + wm + i * 16 + quad * 4;
#pragma unroll
    for (int j = 0; j < 4; ++j) {
      const int col = bn0 + wn + j * 16 + l16;
#pragma unroll
      for (int r = 0; r < 4; ++r) {
        const float v = acc[i][j][r];
        const int m = row + r;
        if (MODE == 0) {
          const int which = col >> 10;
          const int h = (col >> 6) & 15, d = col & 63;
          const int b = m >> 11, n = m & 2047;
          const size_t hh = (size_t)(head_base + b * 16 + h);
          if (which == 0)      q_out[(hh * 2048 + n) * 64 + d] = f2bf(v * QSCALE);
          else if (which == 1) k_out[(hh * 2048 + n) * 64 + d] = f2bf(v);
          else                 v_out[(hh * 64 + d) * 2048 + n] = f2bf(v);  // V^T
        } else {
          const size_t idx = (size_t)m * 1024 + col;
          c_out[idx] = v + bias[col] + res[idx];
        }
      }
    }
  }
}

// ---------------------------------------------------------------- attention
// (R4 structure: XCD-chunked grid, dbuf K/V prefetch, T12 in-register P
// exchange, conflict-free LDS swizzle, native exp2.)
//
// R8: denominator-on-MFMA (R7 idea) with the spill fixed.  R7's regression
// was scratch spill: R6 sat at exactly the 128-reg/wave envelope (64 VGPR +
// sacc 32 + oacc 32); adding lacc(16)+ones(4) spilled (+26 MB HBM traffic).
// Fix: process each 32-key half-tile t SERIALLY (QK^T(t) -> exp/pack(t) ->
// swap(t)), so only one 16-reg sacc and one 8-reg pw are live at a time.
// Peak live ~124 <= 128.  lacc[q] += sum_key P via MFMA32(pa, ones, lacc);
// lacc's reg->row map equals oacc's -> epilogue divides directly, no
// shuffles, no serial rs chain on the VALU stream.
__global__ __launch_bounds__(256, 4) void attn_k(const u16* __restrict__ Q,
                                                 const u16* __restrict__ K,
                                                 const u16* __restrict__ V,
                                                 u16* __restrict__ O) {
  __shared__ alignas(16) u16 kT[2][64 * 64];   // [key][d], granule-swizzled
  __shared__ alignas(16) u16 vT[2][64 * 64];   // [d][key], granule-swizzled

  const int tid = threadIdx.x;
  const int lane = tid & 63, wave = tid >> 6;
  const int qn = lane & 31, h = lane >> 5;

  // XCD-chunked swizzle (bijective: 1024 = 8 XCDs x 128): XCD c owns
  // logical tiles [128c,128c+128) = 16 q-tiles x 8 consecutive heads.
  const int d0 = blockIdx.x;
  const int swz = ((d0 & 7) << 7) | (d0 >> 3);
  const int qx = swz & 15;          // q-tile
  const int hh = (swz >> 4) & 15;   // head-in-group
  const int z  = swz >> 8;          // (s,b)
  const int s = z >> 1, b = z & 1;

  const int head_qk = z * 16 + hh;
  const int head_v  = (z ^ 2) * 16 + hh;            // cross-swapped values
  const u16* Qh = Q + (size_t)head_qk * 2048 * 64;
  const u16* Kh = K + (size_t)head_qk * 2048 * 64;
  const u16* Vh = V + (size_t)head_v * 64 * 2048;   // [d][n]
  const int qr0 = qx * 128 + wave * 32;

  // Q as persistent B-frags: B[k=d=f*16+h*8+j][n=q=qn]
  short8 qf[4];
#pragma unroll
  for (int f = 0; f < 4; ++f)
    qf[f] = *(const short8*)&Qh[(size_t)(qr0 + qn) * 64 + f * 16 + h * 8];

  // all-ones bf16 B-fragment for the denominator MFMA
  short8 ones;
#pragma unroll
  for (int j = 0; j < 8; ++j) ones[j] = (short)0x3F80;

  f32x16 oacc[2] = {};
  f32x16 lacc = {};

  const int srow = lane >> 3;

  union PU { unsigned u[4]; short8 s; };

  auto stage = [&](int buf, int j0) {
#pragma unroll
    for (int it = 0; it < 2; ++it) {
      const int rb = wave * 16 + it * 8;
      const int r = rb + srow;
      const int sgx = (lane & 7) ^ srow ^ (rb >> 3);  // inverse of read key
      load_lds16(&Kh[(size_t)(j0 + r) * 64 + sgx * 8], &kT[buf][rb * 64]);
      load_lds16(&Vh[(size_t)r * 2048 + j0 + sgx * 8], &vT[buf][rb * 64]);
    }
  };

  stage(0, 0);
  asm volatile("s_waitcnt vmcnt(0)" ::: "memory");
  __syncthreads();

  int cur = 0;
  for (int j0 = 0; j0 < 2048; j0 += 64) {
    if (j0 + 64 < 2048) stage(cur ^ 1, j0 + 64);  // prefetch under compute
    const u16* kb = kT[cur];
    const u16* vb = vT[cur];

    // per 32-key half-tile t: S^T = K*Q^T -> p=exp2(s) -> pack -> swap.
    // Serial over t keeps only one sacc (16) + one pw (8) live -> no spill.
    PU pa[4];
#pragma unroll
    for (int t = 0; t < 2; ++t) {
      f32x16 sacc = {};
      const int row = t * 32 + qn;
      const int key = (row & 7) ^ (row >> 3);  // conflict-free swizzle key
#pragma unroll
      for (int kd = 0; kd < 4; ++kd) {
        const int go = ((kd * 2 + h) ^ key) * 8;
        const short8 kf = *(const short8*)&kb[row * 64 + go];
        sacc = MFMA32(kf, qf[kd], sacc);
      }

      unsigned pw[8];
#pragma unroll
      for (int j = 0; j < 8; ++j) {
        const float p0 = __builtin_amdgcn_exp2f(sacc[2 * j]);
        const float p1 = __builtin_amdgcn_exp2f(sacc[2 * j + 1]);
        pw[j] = cvt_pk_bf16(p0, p1);
      }

      // h-half exchange (T12): lane(h=0) holds keys ≡0..3 (mod 8), lane^32
      // holds ≡4..7.  swap(w[4e],w[4e+2]) / swap(w[4e+1],w[4e+3]) yields
      // pa[st][j] = P[q=qn][key=st*16+h*8+j] for st=2t+e.
#pragma unroll
      for (int e = 0; e < 2; ++e) {
        unsigned a0 = pw[4 * e + 0], a2 = pw[4 * e + 2];
        unsigned a1 = pw[4 * e + 1], a3 = pw[4 * e + 3];
        plswap(a0, a2);
        plswap(a1, a3);
        pa[2 * t + e].u[0] = a0; pa[2 * t + e].u[1] = a1;
        pa[2 * t + e].u[2] = a2; pa[2 * t + e].u[3] = a3;
      }
    }

    // denominator on the MFMA pipe: lacc[q] += sum_key P[q][key]
#pragma unroll
    for (int st = 0; st < 4; ++st)
      lacc = MFMA32(pa[st].s, ones, lacc);

    // O += P * V: A = P[q][key], B = V[key][d] (from vT[d][key])
#pragma unroll
    for (int dt = 0; dt < 2; ++dt) {
      const int row = dt * 32 + qn;
      const int key = (row & 7) ^ (row >> 3);
#pragma unroll
      for (int st = 0; st < 4; ++st) {
        const int go = ((st * 2 + h) ^ key) * 8;
        const short8 vf = *(const short8*)&vb[row * 64 + go];
        oacc[dt] = MFMA32(pa[st].s, vf, oacc[dt]);
      }
    }

    asm volatile("s_waitcnt vmcnt(0)" ::: "memory");  // prefetch landed
    __syncthreads();  // all waves done reading cur; next buf visible
    cur ^= 1;
  }

  // epilogue: O[q][d]: row q=(reg&3)+8*(reg>>2)+4h, col d=dt*32+qn.
  // lacc[r] has the same reg->row mapping -> direct divide, no shuffles.
  u16* Ob = O + (size_t)s * 4096 * 1024;
#pragma unroll
  for (int r = 0; r < 16; ++r) {
    const int qrow = (r & 3) + 8 * (r >> 2) + 4 * h;
    const float inv = 1.f / lacc[r];
    const size_t base = (size_t)(b * 2048 + qr0 + qrow) * 1024 + hh * 64;
#pragma unroll
    for (int dt = 0; dt < 2; ++dt)
      Ob[base + dt * 32 + qn] = f2bf(oacc[dt][r] * inv);
  }
}

// ---------------------------------------------------------------- launch
extern "C" void kernel_launch(void* const* d_in, const int* in_sizes, int n_in,
                              void* d_out, int out_size, void* d_ws, size_t ws_size,
                              hipStream_t stream) {
  const float* x      = (const float*)d_in[0];   // [2,2048,1024] f32
  const float* y      = (const float*)d_in[1];
  const float* w_qkv  = (const float*)d_in[2];   // [1024,3072] f32
  const float* w_proj = (const float*)d_in[3];   // [1024,1024] f32
  const float* b_proj = (const float*)d_in[4];   // [1024] f32
  float* out = (float*)d_out;                    // 2 x [2,2048,1024] f32

  u16* xb     = (u16*)d_ws;
  u16* yb     = xb + 4194304;
  u16* Ob     = xb;                 // reuse: xb/yb dead after QKV GEMMs
  u16* wqkvT  = yb + 4194304;       // [3072][1024]
  u16* wprojT = wqkvT + 3145728;    // [1024][1024]
  u16* Qs     = wprojT + 1048576;   // [64][2048][64]
  u16* Ks     = Qs + 8388608;       // [64][2048][64]
  u16* Vs     = Ks + 8388608;       // [64][64][2048]  (transposed)

  cvt2_k<<<dim3(2048, 2), 256, 0, stream>>>(x, y, xb, yb);
  cvtT_k<<<dim3(48, 16), 256, 0, stream>>>(w_qkv, wqkvT, 1024, 3072);
  cvtT_k<<<dim3(16, 16), 256, 0, stream>>>(w_proj, wprojT, 1024, 1024);

  gemm_k<0><<<1536, 256, 0, stream>>>(xb, yb, wqkvT, Qs, Ks, Vs,
                                      nullptr, nullptr, nullptr,
                                      nullptr, nullptr);

  attn_k<<<1024, 256, 0, stream>>>(Qs, Ks, Vs, Ob);

  gemm_k<1><<<512, 256, 0, stream>>>(Ob, Ob + 4194304, wprojT,
                                     nullptr, nullptr, nullptr,
                                     out, out + 4194304, b_proj, x, y);
}

// Round 9
// 262.026 us; speedup vs baseline: 1.1767x; 1.1242x over previous
//
#include <hip/hip_runtime.h>

using u16    = unsigned short;
using short8 = __attribute__((ext_vector_type(8))) short;
using f32x4  = __attribute__((ext_vector_type(4))) float;
using f32x16 = __attribute__((ext_vector_type(16))) float;

#define MFMA16(a, b, c) __builtin_amdgcn_mfma_f32_16x16x32_bf16(a, b, c, 0, 0, 0)
#define MFMA32(a, b, c) __builtin_amdgcn_mfma_f32_32x32x16_bf16(a, b, c, 0, 0, 0)

// 0.125 (= D^-0.5) * log2(e): folded into Q so softmax uses exp2 directly.
#define QSCALE 0.18033688011112042f

__device__ inline u16 f2bf(float f) {
  union { float f; unsigned u; } v; v.f = f;
  unsigned r = v.u + 0x7fffu + ((v.u >> 16) & 1u);  // RTN-even
  return (u16)(r >> 16);
}

// async global->LDS, 16B/lane; LDS dest = wave-uniform base + lane*16
__device__ __forceinline__ void load_lds16(const u16* g, u16* l) {
  __builtin_amdgcn_global_load_lds((const __attribute__((address_space(1))) void*)g,
                                   (__attribute__((address_space(3))) void*)l, 16, 0, 0);
}

// packed f32 pair -> bf16x2 word (lo in low 16, hi in high 16), RTNE
__device__ __forceinline__ unsigned cvt_pk_bf16(float lo, float hi) {
  unsigned r;
  asm("v_cvt_pk_bf16_f32 %0, %1, %2" : "=v"(r) : "v"(lo), "v"(hi));
  return r;
}

// swap a's high 32 lanes with b's low 32 lanes (v_permlane32_swap_b32)
__device__ __forceinline__ void plswap(unsigned& a, unsigned& b) {
  auto r = __builtin_amdgcn_permlane32_swap(a, b, false, false);
  a = r[0];
  b = r[1];
}

// ------------------------------------------------------------ f32 -> bf16
// Both x and y in one launch: blockIdx.y selects the tensor.
__global__ __launch_bounds__(256) void cvt2_k(const float* __restrict__ s0,
                                              const float* __restrict__ s1,
                                              u16* __restrict__ d0,
                                              u16* __restrict__ d1) {
  const float* src = blockIdx.y ? s1 : s0;
  u16* dst = blockIdx.y ? d1 : d0;
  const int i = (blockIdx.x * 256 + threadIdx.x) * 8;
  const float4 a = *(const float4*)&src[i];
  const float4 b = *(const float4*)&src[i + 4];
  short8 o;
  o[0] = (short)f2bf(a.x); o[1] = (short)f2bf(a.y);
  o[2] = (short)f2bf(a.z); o[3] = (short)f2bf(a.w);
  o[4] = (short)f2bf(b.x); o[5] = (short)f2bf(b.y);
  o[6] = (short)f2bf(b.z); o[7] = (short)f2bf(b.w);
  *(short8*)&dst[i] = o;
}

// ------------------------------------------- f32 [R][C] -> bf16 [C][R]
__global__ __launch_bounds__(256) void cvtT_k(const float* __restrict__ src,
                                              u16* __restrict__ dst, int R, int C) {
  __shared__ float t[64][65];
  const int c0 = blockIdx.x * 64, r0 = blockIdx.y * 64;
  const int lc = threadIdx.x & 63, g = threadIdx.x >> 6;
#pragma unroll
  for (int i = 0; i < 16; ++i) {
    const int r = g + i * 4;
    t[r][lc] = src[(size_t)(r0 + r) * C + c0 + lc];
  }
  __syncthreads();
#pragma unroll
  for (int i = 0; i < 16; ++i) {
    const int c = g + i * 4;
    dst[(size_t)(c0 + c) * R + r0 + lc] = f2bf(t[lc][c]);
  }
}

// ---------------------------------------------------------------- GEMM 128²
// C[m][n] = sum_k A[m][k] * Bt[n][k].  K = 1024 bf16, strides 1024.
// Block tile 128x128, BK=64; 4 waves (2x2), wave 64x64 via 4x4 MFMA 16x16x32.
// Single-buffer staging (m97 structure; R5: 256² 8-phase regressed here).
// T1 XCD-chunked 1-D grid.
//
// R9: __launch_bounds__(256, 4) -- the m97 structure lives on wave-level
// overlap across co-resident blocks (m114); (256,2) let VGPR grow past 128
// and capped us at 2 blocks/CU, exposing the per-iter stage stall.  Register
// demand ~116 (acc 64 + frags 32 + addressing) fits 128 without spill.
// Also: V^T epilogue stores packed 4x u16 -> 1x 8B (bitwise identical).
template <int MODE>
__global__ __launch_bounds__(256, 4) void gemm_k(
    const u16* __restrict__ A0, const u16* __restrict__ A1,
    const u16* __restrict__ Bt,
    u16* __restrict__ q_out, u16* __restrict__ k_out, u16* __restrict__ v_out,
    float* __restrict__ c0, float* __restrict__ c1,
    const float* __restrict__ bias,
    const float* __restrict__ res0, const float* __restrict__ res1) {
  __shared__ alignas(16) u16 lA[128 * 64];
  __shared__ alignas(16) u16 lB[128 * 64];

  const int nx = (MODE == 0) ? 24 : 8;        // N/128
  const int nb = nx * 32 * 2;                  // total tiles (y=32, z=2)
  const int bi = blockIdx.x;
  const int L  = (bi & 7) * (nb >> 3) + (bi >> 3);
  const int xt = L % nx;
  const int yt = (L / nx) & 31;
  const int z  = L / (nx * 32);

  const u16* A = z ? A1 : A0;
  float* c_out = z ? c1 : c0;
  const float* res = z ? res1 : res0;
  const int head_base = z * 32;

  const int tid = threadIdx.x;
  const int lane = tid & 63, wave = tid >> 6;
  const int quad = lane >> 4, l16 = lane & 15;
  const int lsw = (l16 & 7) * 8;
  const int wm = (wave >> 1) * 64, wn = (wave & 1) * 64;
  const int bn0 = xt * 128, bm0 = yt * 128;
  const int srow = lane >> 3;
  const int sg = (lane & 7) ^ srow;

  f32x4 acc[4][4] = {};

  for (int k0 = 0; k0 < 1024; k0 += 64) {
    __syncthreads();
#pragma unroll
    for (int it = 0; it < 4; ++it) {
      const int rb = wave * 32 + it * 8;
      const int r = rb + srow;
      load_lds16(&A[(size_t)(bm0 + r) * 1024 + k0 + sg * 8], &lA[rb * 64]);
      load_lds16(&Bt[(size_t)(bn0 + r) * 1024 + k0 + sg * 8], &lB[rb * 64]);
    }
    asm volatile("s_waitcnt vmcnt(0)" ::: "memory");
    __syncthreads();
#pragma unroll
    for (int kt = 0; kt < 2; ++kt) {
      short8 af[4], bfr[4];
#pragma unroll
      for (int i = 0; i < 4; ++i) {
        const int go = ((kt * 4 + quad) * 8) ^ lsw;
        af[i]  = *(const short8*)&lA[(wm + i * 16 + l16) * 64 + go];
        bfr[i] = *(const short8*)&lB[(wn + i * 16 + l16) * 64 + go];
      }
#pragma unroll
      for (int i = 0; i < 4; ++i)
#pragma unroll
        for (int j = 0; j < 4; ++j)
          acc[i][j] = MFMA16(af[i], bfr[j], acc[i][j]);
    }
  }

#pragma unroll
  for (int i = 0; i < 4; ++i) {
    const int row = bm0 + wm + i * 16 + quad * 4;   // quad*4-aligned
#pragma unroll
    for (int j = 0; j < 4; ++j) {
      const int col = bn0 + wn + j * 16 + l16;
      if (MODE == 0) {
        const int which = col >> 10;
        const int h = (col >> 6) & 15, d = col & 63;
        const int b = row >> 11, n0 = row & 2047;   // constant over r (aligned)
        const size_t hh = (size_t)(head_base + b * 16 + h);
        if (which == 2) {
          // V^T [d][n]: 4 consecutive tokens -> one 8B store
          union { u16 pk[4]; uint2 v; } u;
#pragma unroll
          for (int r = 0; r < 4; ++r) u.pk[r] = f2bf(acc[i][j][r]);
          *(uint2*)&v_out[(hh * 64 + d) * 2048 + n0] = u.v;
        } else if (which == 0) {
#pragma unroll
          for (int r = 0; r < 4; ++r)
            q_out[(hh * 2048 + n0 + r) * 64 + d] = f2bf(acc[i][j][r] * QSCALE);
        } else {
#pragma unroll
          for (int r = 0; r < 4; ++r)
            k_out[(hh * 2048 + n0 + r) * 64 + d] = f2bf(acc[i][j][r]);
        }
      } else {
#pragma unroll
        for (int r = 0; r < 4; ++r) {
          const int m = row + r;
          const size_t idx = (size_t)m * 1024 + col;
          c_out[idx] = acc[i][j][r] + bias[col] + res[idx];
        }
      }
    }
  }
}

// ---------------------------------------------------------------- attention
// (R8 final: XCD-chunked grid, dbuf K/V prefetch, T12 in-register P exchange,
// conflict-free LDS swizzle, native exp2, denominator on the MFMA pipe with
// serial half-tile processing to stay within the 128-reg/wave envelope.
// 86.8 us, 790 TF, VALU 44 / MFMA 44 -- dependency-bound; further gains need
// the full T16 co-design.)
__global__ __launch_bounds__(256, 4) void attn_k(const u16* __restrict__ Q,
                                                 const u16* __restrict__ K,
                                                 const u16* __restrict__ V,
                                                 u16* __restrict__ O) {
  __shared__ alignas(16) u16 kT[2][64 * 64];   // [key][d], granule-swizzled
  __shared__ alignas(16) u16 vT[2][64 * 64];   // [d][key], granule-swizzled

  const int tid = threadIdx.x;
  const int lane = tid & 63, wave = tid >> 6;
  const int qn = lane & 31, h = lane >> 5;

  // XCD-chunked swizzle (bijective: 1024 = 8 XCDs x 128): XCD c owns
  // logical tiles [128c,128c+128) = 16 q-tiles x 8 consecutive heads.
  const int d0 = blockIdx.x;
  const int swz = ((d0 & 7) << 7) | (d0 >> 3);
  const int qx = swz & 15;          // q-tile
  const int hh = (swz >> 4) & 15;   // head-in-group
  const int z  = swz >> 8;          // (s,b)
  const int s = z >> 1, b = z & 1;

  const int head_qk = z * 16 + hh;
  const int head_v  = (z ^ 2) * 16 + hh;            // cross-swapped values
  const u16* Qh = Q + (size_t)head_qk * 2048 * 64;
  const u16* Kh = K + (size_t)head_qk * 2048 * 64;
  const u16* Vh = V + (size_t)head_v * 64 * 2048;   // [d][n]
  const int qr0 = qx * 128 + wave * 32;

  // Q as persistent B-frags: B[k=d=f*16+h*8+j][n=q=qn]
  short8 qf[4];
#pragma unroll
  for (int f = 0; f < 4; ++f)
    qf[f] = *(const short8*)&Qh[(size_t)(qr0 + qn) * 64 + f * 16 + h * 8];

  // all-ones bf16 B-fragment for the denominator MFMA
  short8 ones;
#pragma unroll
  for (int j = 0; j < 8; ++j) ones[j] = (short)0x3F80;

  f32x16 oacc[2] = {};
  f32x16 lacc = {};

  const int srow = lane >> 3;

  union PU { unsigned u[4]; short8 s; };

  auto stage = [&](int buf, int j0) {
#pragma unroll
    for (int it = 0; it < 2; ++it) {
      const int rb = wave * 16 + it * 8;
      const int r = rb + srow;
      const int sgx = (lane & 7) ^ srow ^ (rb >> 3);  // inverse of read key
      load_lds16(&Kh[(size_t)(j0 + r) * 64 + sgx * 8], &kT[buf][rb * 64]);
      load_lds16(&Vh[(size_t)r * 2048 + j0 + sgx * 8], &vT[buf][rb * 64]);
    }
  };

  stage(0, 0);
  asm volatile("s_waitcnt vmcnt(0)" ::: "memory");
  __syncthreads();

  int cur = 0;
  for (int j0 = 0; j0 < 2048; j0 += 64) {
    if (j0 + 64 < 2048) stage(cur ^ 1, j0 + 64);  // prefetch under compute
    const u16* kb = kT[cur];
    const u16* vb = vT[cur];

    // per 32-key half-tile t: S^T = K*Q^T -> p=exp2(s) -> pack -> swap.
    // Serial over t keeps only one sacc (16) + one pw (8) live -> no spill.
    PU pa[4];
#pragma unroll
    for (int t = 0; t < 2; ++t) {
      f32x16 sacc = {};
      const int row = t * 32 + qn;
      const int key = (row & 7) ^ (row >> 3);  // conflict-free swizzle key
#pragma unroll
      for (int kd = 0; kd < 4; ++kd) {
        const int go = ((kd * 2 + h) ^ key) * 8;
        const short8 kf = *(const short8*)&kb[row * 64 + go];
        sacc = MFMA32(kf, qf[kd], sacc);
      }

      unsigned pw[8];
#pragma unroll
      for (int j = 0; j < 8; ++j) {
        const float p0 = __builtin_amdgcn_exp2f(sacc[2 * j]);
        const float p1 = __builtin_amdgcn_exp2f(sacc[2 * j + 1]);
        pw[j] = cvt_pk_bf16(p0, p1);
      }

      // h-half exchange (T12): lane(h=0) holds keys ≡0..3 (mod 8), lane^32
      // holds ≡4..7.  swap(w[4e],w[4e+2]) / swap(w[4e+1],w[4e+3]) yields
      // pa[st][j] = P[q=qn][key=st*16+h*8+j] for st=2t+e.
#pragma unroll
      for (int e = 0; e < 2; ++e) {
        unsigned a0 = pw[4 * e + 0], a2 = pw[4 * e + 2];
        unsigned a1 = pw[4 * e + 1], a3 = pw[4 * e + 3];
        plswap(a0, a2);
        plswap(a1, a3);
        pa[2 * t + e].u[0] = a0; pa[2 * t + e].u[1] = a1;
        pa[2 * t + e].u[2] = a2; pa[2 * t + e].u[3] = a3;
      }
    }

    // denominator on the MFMA pipe: lacc[q] += sum_key P[q][key]
#pragma unroll
    for (int st = 0; st < 4; ++st)
      lacc = MFMA32(pa[st].s, ones, lacc);

    // O += P * V: A = P[q][key], B = V[key][d] (from vT[d][key])
#pragma unroll
    for (int dt = 0; dt < 2; ++dt) {
      const int row = dt * 32 + qn;
      const int key = (row & 7) ^ (row >> 3);
#pragma unroll
      for (int st = 0; st < 4; ++st) {
        const int go = ((st * 2 + h) ^ key) * 8;
        const short8 vf = *(const short8*)&vb[row * 64 + go];
        oacc[dt] = MFMA32(pa[st].s, vf, oacc[dt]);
      }
    }

    asm volatile("s_waitcnt vmcnt(0)" ::: "memory");  // prefetch landed
    __syncthreads();  // all waves done reading cur; next buf visible
    cur ^= 1;
  }

  // epilogue: O[q][d]: row q=(reg&3)+8*(reg>>2)+4h, col d=dt*32+qn.
  // lacc[r] has the same reg->row mapping -> direct divide, no shuffles.
  u16* Ob = O + (size_t)s * 4096 * 1024;
#pragma unroll
  for (int r = 0; r < 16; ++r) {
    const int qrow = (r & 3) + 8 * (r >> 2) + 4 * h;
    const float inv = 1.f / lacc[r];
    const size_t base = (size_t)(b * 2048 + qr0 + qrow) * 1024 + hh * 64;
#pragma unroll
    for (int dt = 0; dt < 2; ++dt)
      Ob[base + dt * 32 + qn] = f2bf(oacc[dt][r] * inv);
  }
}

// ---------------------------------------------------------------- launch
extern "C" void kernel_launch(void* const* d_in, const int* in_sizes, int n_in,
                              void* d_out, int out_size, void* d_ws, size_t ws_size,
                              hipStream_t stream) {
  const float* x      = (const float*)d_in[0];   // [2,2048,1024] f32
  const float* y      = (const float*)d_in[1];
  const float* w_qkv  = (const float*)d_in[2];   // [1024,3072] f32
  const float* w_proj = (const float*)d_in[3];   // [1024,1024] f32
  const float* b_proj = (const float*)d_in[4];   // [1024] f32
  float* out = (float*)d_out;                    // 2 x [2,2048,1024] f32

  u16* xb     = (u16*)d_ws;
  u16* yb     = xb + 4194304;
  u16* Ob     = xb;                 // reuse: xb/yb dead after QKV GEMMs
  u16* wqkvT  = yb + 4194304;       // [3072][1024]
  u16* wprojT = wqkvT + 3145728;    // [1024][1024]
  u16* Qs     = wprojT + 1048576;   // [64][2048][64]
  u16* Ks     = Qs + 8388608;       // [64][2048][64]
  u16* Vs     = Ks + 8388608;       // [64][64][2048]  (transposed)

  cvt2_k<<<dim3(2048, 2), 256, 0, stream>>>(x, y, xb, yb);
  cvtT_k<<<dim3(48, 16), 256, 0, stream>>>(w_qkv, wqkvT, 1024, 3072);
  cvtT_k<<<dim3(16, 16), 256, 0, stream>>>(w_proj, wprojT, 1024, 1024);

  gemm_k<0><<<1536, 256, 0, stream>>>(xb, yb, wqkvT, Qs, Ks, Vs,
                                      nullptr, nullptr, nullptr,
                                      nullptr, nullptr);

  attn_k<<<1024, 256, 0, stream>>>(Qs, Ks, Vs, Ob);

  gemm_k<1><<<512, 256, 0, stream>>>(Ob, Ob + 4194304, wprojT,
                                     nullptr, nullptr, nullptr,
                                     out, out + 4194304, b_proj, x, y);
}